// Round 6
// baseline (615.558 us; speedup 1.0000x reference)
//
#include <hip/hip_runtime.h>
#include <hip/hip_bf16.h>
#include <stdint.h>

// Problem constants
#define BATCH 256
#define SEQT  200
#define IND   128
#define HID   256
#define G3    768   // 3*HID
#define OUTD  118

#define HSTRIDE 264  // h-state LDS row stride in shorts (16B-aligned; 132 dw ≡ 4 mod 32)
#define W0SZ (G3*IND)
#define WHSZ (G3*HID)
#define XSZ  (BATCH*SEQT*IND)   // 6,553,600 floats

#define LOG2E  1.44269504f
#define NLOG2E (-1.44269504f)
#define LOG2E2 2.88539008f

typedef short  short8 __attribute__((ext_vector_type(8)));
typedef float  f32x4  __attribute__((ext_vector_type(4)));
typedef int    i32x4  __attribute__((ext_vector_type(4)));

__device__ __forceinline__ float exp2fast(float x) {
#if __has_builtin(__builtin_amdgcn_exp2f)
    return __builtin_amdgcn_exp2f(x);
#else
    return exp2f(x);
#endif
}

__device__ __forceinline__ unsigned short f2bf(float x) {
    union { float f; uint32_t u; } v; v.f = x;
    uint32_t u = v.u;
    u += 0x7FFF + ((u >> 16) & 1);   // round-to-nearest-even
    return (unsigned short)(u >> 16);
}

// One fused, float4-vectorized conversion kernel: x + all four weight matrices.
// All region sizes are divisible by 4, so a 4-chunk never crosses a boundary.
__global__ void cvt_all(const float* __restrict__ x,
                        const float* __restrict__ w0,  const float* __restrict__ wh0,
                        const float* __restrict__ w1,  const float* __restrict__ wh1,
                        unsigned short* __restrict__ xb,
                        unsigned short* __restrict__ o0,  unsigned short* __restrict__ oh0,
                        unsigned short* __restrict__ o1,  unsigned short* __restrict__ oh1) {
    const int n4 = (XSZ + W0SZ + 3 * WHSZ) / 4;
    int idx = blockIdx.x * blockDim.x + threadIdx.x;
    int stride = gridDim.x * blockDim.x;
    for (int i = idx; i < n4; i += stride) {
        int j = i * 4;
        const float* src; unsigned short* dst;
        if (j < XSZ) { src = x; dst = xb; }
        else {
            j -= XSZ;
            if (j < W0SZ) { src = w0; dst = o0; }
            else {
                j -= W0SZ;
                if (j < WHSZ) { src = wh0; dst = oh0; }
                else {
                    j -= WHSZ;
                    if (j < WHSZ) { src = w1; dst = o1; }
                    else { j -= WHSZ; src = wh1; dst = oh1; }
                }
            }
        }
        float4 v = *(const float4*)(src + j);
        ushort4 o;
        o.x = f2bf(v.x); o.y = f2bf(v.y); o.z = f2bf(v.z); o.w = f2bf(v.w);
        *(ushort4*)(dst + j) = o;
    }
}

// bc = bih + bhh for r,z gates (j < 512); bc = bih for n gate. Both layers.
__global__ void combine_bias(const float* __restrict__ bih0, const float* __restrict__ bhh0,
                             const float* __restrict__ bih1, const float* __restrict__ bhh1,
                             float* __restrict__ bc0, float* __restrict__ bc1) {
    int i = blockIdx.x * blockDim.x + threadIdx.x;
    if (i < G3) bc0[i] = bih0[i] + (i < 2 * HID ? bhh0[i] : 0.0f);
    else if (i < 2 * G3) {
        int j = i - G3;
        bc1[j] = bih1[j] + (j < 2 * HID ? bhh1[j] : 0.0f);
    }
}

// C[M,768] = scale * (A[M,K] @ Bt[768,K]^T + bias), scale = -log2e (r,z) / +2*log2e (n).
// grid = (6, M/128): nb = blockIdx.x (fast dim -> the 6 nb-siblings of a panel are
// dispatch-adjacent, keeping the A panel L2/L3-hot across its 6 re-reads).
// A panel [128][K] staged into LDS with coalesced 16B/lane loads; LDS rows padded
// to LSTRIDE = K/8+1 16B-units (odd -> conflict-free ds_read_b128 fragments).
// B fragments pinned in regs (issued before staging; latency hides under it).
template<int K>
__global__ __launch_bounds__(256) void gemm_bn(
    const unsigned short* __restrict__ A,
    const unsigned short* __restrict__ Bt,
    const float* __restrict__ bias,
    float* __restrict__ C)
{
    constexpr int KS      = K / 32;     // MFMA k-steps
    constexpr int CPR     = K / 8;      // 16B chunks per A row
    constexpr int LSTRIDE = CPR + 1;    // padded LDS row stride (16B units)
    constexpr int NCH     = 128 * CPR;  // chunks per panel
    constexpr int PT      = NCH / 256;  // chunks per thread (16 or 8)

    __shared__ i32x4 sA[128 * LSTRIDE];   // 67.6KB (K=256) / 34.8KB (K=128)

    const int tid  = threadIdx.x;
    const int wave = tid >> 6;
    const int lane = tid & 63;
    const int col  = lane & 15;
    const int quad = lane >> 4;
    const int nb   = blockIdx.x;
    const int g0   = nb * 128 + wave * 32 + col;   // jt0 output column
    const float scl = (nb < 4) ? NLOG2E : LOG2E2;
    const int m_panel = blockIdx.y * 128;

    // B fragments -> regs (issue first: long-latency gathers hide under staging)
    short8 b[2][KS];
#pragma unroll
    for (int jt = 0; jt < 2; jt++)
#pragma unroll
        for (int ks = 0; ks < KS; ks++)
            b[jt][ks] = *(const short8*)(Bt + (size_t)(g0 + jt * 16) * K + ks * 32 + quad * 8);

    // stage A panel -> LDS, coalesced (wave reads 1024B contiguous per instr)
    const unsigned short* ap = A + (size_t)m_panel * K;
    i32x4 st[PT];
#pragma unroll
    for (int i = 0; i < PT; i++)
        st[i] = *(const i32x4*)(ap + (size_t)(i * 256 + tid) * 8);
#pragma unroll
    for (int i = 0; i < PT; i++) {
        int g   = i * 256 + tid;
        int row = g / CPR;          // pow2 -> shift
        int c   = g % CPR;
        sA[row * LSTRIDE + c] = st[i];
    }
    __syncthreads();

    const float bia0 = bias[g0];
    const float bia1 = bias[g0 + 16];

#pragma unroll 2
    for (int ms = 0; ms < 8; ms++) {
        f32x4 acc0 = (f32x4)(0.0f), acc1 = (f32x4)(0.0f);
#pragma unroll
        for (int ks = 0; ks < KS; ks++) {
            short8 a = __builtin_bit_cast(short8,
                sA[(ms * 16 + col) * LSTRIDE + ks * 4 + quad]);
            acc0 = __builtin_amdgcn_mfma_f32_16x16x32_bf16(a, b[0][ks], acc0, 0, 0, 0);
            acc1 = __builtin_amdgcn_mfma_f32_16x16x32_bf16(a, b[1][ks], acc1, 0, 0, 0);
        }

        float* crow = C + (size_t)(m_panel + ms * 16 + quad * 4) * G3 + g0;
#pragma unroll
        for (int r = 0; r < 4; r++) {
            crow[(size_t)r * G3]      = (acc0[r] + bia0) * scl;
            crow[(size_t)r * G3 + 16] = (acc1[r] + bia1) * scl;
        }
    }
}

// GRU scan. 256 WGs x 512 threads (8 waves, 2/SIMD @ 256-reg budget) -- ALL CUs.
// WG owns ONE batch, placed at MFMA row 0; all quads read the SAME gx row
// (broadcast loads: one coalesced 3KB row per WG per step; per-CU HBM share
// 4x lower than the 64-WG version, 4x the aggregate fetch concurrency).
// Rows 4/8/12 of the MFMA tile compute garbage-but-finite values (h stays
// bounded: z in (0,1), n in (-1,1)) that only touch unused output rows;
// global stores are guarded to quad==0. All Whh weights pinned in 192
// VGPRs/wave; per-step LDS = 8 h-fragment b128 reads only. gx for step t+1
// prefetched into registers during step t.
__global__ __launch_bounds__(512, 2) void gru_scan(
    const float* __restrict__ gx,            // [B*T,768] pre-scaled exp2 args (+pad)
    const unsigned short* __restrict__ Whh,  // [768,256] bf16
    const float* __restrict__ bhh,           // [768] (only n-part used)
    unsigned short* __restrict__ h1_out,     // [B*T,256] bf16 or nullptr
    float* __restrict__ hlast)               // [B,256] fp32 or nullptr
{
    __shared__ unsigned short hs[2][16 * HSTRIDE];   // 16,896 B (all LDS we use)

    const int b0    = blockIdx.x;         // one batch per WG
    const int tid   = threadIdx.x;
    const int wave  = tid >> 6;
    const int lane  = tid & 63;
    const int col   = lane & 15;
    const int quad  = lane >> 4;
    const int jbase = wave * 32;
    const int j0    = jbase + col;        // jt0 column
    const int j1    = jbase + 16 + col;   // jt1 column

    // r,z weights (both jt) -> pinned registers: 128 VGPRs
    i32x4 wrz[2][2][8];   // [gate][jt][ks]
#pragma unroll
    for (int g = 0; g < 2; g++)
#pragma unroll
        for (int jt = 0; jt < 2; jt++)
#pragma unroll
            for (int ks = 0; ks < 8; ks++)
                wrz[g][jt][ks] = *(const i32x4*)(
                    Whh + (size_t)(g * HID + jbase + jt * 16 + col) * HID + ks * 32 + quad * 8);

    // n-gate jt0 -> pinned registers: 32 VGPRs
    i32x4 wn0[8];
#pragma unroll
    for (int ks = 0; ks < 8; ks++)
        wn0[ks] = *(const i32x4*)(
            Whh + (size_t)(2 * HID + j0) * HID + ks * 32 + quad * 8);

    // n-gate jt1 -> pinned registers: 32 VGPRs
    i32x4 wn1r[8];
#pragma unroll
    for (int ks = 0; ks < 8; ks++)
        wn1r[ks] = *(const i32x4*)(
            Whh + (size_t)(2 * HID + j1) * HID + ks * 32 + quad * 8);

    // zero BOTH h buffers (padding rows stay finite; row 0 is the live batch)
    for (int i = tid; i < 2 * 16 * HSTRIDE; i += 512) ((unsigned short*)hs)[i] = 0;

    float hreg[2] = {};
    float bhn[2] = { bhh[2 * HID + j0], bhh[2 * HID + j1] };

    int gof, hof;
    {
        int row = b0 * SEQT;              // same row for all quads -> broadcast
        gof = row * G3 + j0;
        hof = row * HID + j0;
    }
    const int abase = col * HSTRIDE + quad * 8;          // A-frag read base (shorts)
    const int wbase = (quad * 4) * HSTRIDE + j0;         // h write base (row = quad*4)

    __syncthreads();

    // preload gx for t=0
    float gc[3][2];
#pragma unroll
    for (int g3 = 0; g3 < 3; g3++) {
        gc[g3][0] = gx[gof + g3 * HID];
        gc[g3][1] = gx[gof + g3 * HID + 16];
    }
    gof += G3;

    for (int t = 0; t < SEQT; t++) {
        const unsigned short* hc = hs[t & 1];
        unsigned short*       hn = hs[(t & 1) ^ 1];

        // pin weight regs: opaque per-iter redefinition blocks remat/sinking
#pragma unroll
        for (int g = 0; g < 2; g++)
#pragma unroll
            for (int jt = 0; jt < 2; jt++)
#pragma unroll
                for (int ks = 0; ks < 8; ks++)
                    asm volatile("" : "+v"(wrz[g][jt][ks]));
#pragma unroll
        for (int ks = 0; ks < 8; ks++) {
            asm volatile("" : "+v"(wn0[ks]));
            asm volatile("" : "+v"(wn1r[ks]));
        }

        // prefetch gx for t+1 (gxb is tail-padded; t=199 loads are discarded)
        float gcn[3][2];
#pragma unroll
        for (int g3 = 0; g3 < 3; g3++) {
            gcn[g3][0] = gx[gof + g3 * HID];
            gcn[g3][1] = gx[gof + g3 * HID + 16];
        }
        gof += G3;

        f32x4 acc[3][2];
#pragma unroll
        for (int g = 0; g < 3; g++)
#pragma unroll
            for (int jt = 0; jt < 2; jt++) acc[g][jt] = (f32x4)(0.0f);

        __builtin_amdgcn_s_setprio(1);
#pragma unroll
        for (int ks = 0; ks < 8; ks++) {
            short8 a = *(const short8*)(&hc[abase + ks * 32]);
            acc[0][0] = __builtin_amdgcn_mfma_f32_16x16x32_bf16(a, __builtin_bit_cast(short8, wrz[0][0][ks]), acc[0][0], 0, 0, 0);
            acc[0][1] = __builtin_amdgcn_mfma_f32_16x16x32_bf16(a, __builtin_bit_cast(short8, wrz[0][1][ks]), acc[0][1], 0, 0, 0);
            acc[1][0] = __builtin_amdgcn_mfma_f32_16x16x32_bf16(a, __builtin_bit_cast(short8, wrz[1][0][ks]), acc[1][0], 0, 0, 0);
            acc[1][1] = __builtin_amdgcn_mfma_f32_16x16x32_bf16(a, __builtin_bit_cast(short8, wrz[1][1][ks]), acc[1][1], 0, 0, 0);
            acc[2][0] = __builtin_amdgcn_mfma_f32_16x16x32_bf16(a, __builtin_bit_cast(short8, wn0[ks]),       acc[2][0], 0, 0, 0);
            acc[2][1] = __builtin_amdgcn_mfma_f32_16x16x32_bf16(a, __builtin_bit_cast(short8, wn1r[ks]),      acc[2][1], 0, 0, 0);
        }
        __builtin_amdgcn_s_setprio(0);

        unsigned short hb[2];
#pragma unroll
        for (int jt = 0; jt < 2; jt++) {
            // sigmoid(p) = 1/(1+exp2(-log2e*p)); gc holds -log2e*(gx+b)
            float er = exp2fast(__builtin_fmaf(acc[0][jt][0], NLOG2E, gc[0][jt]));
            float rr = __builtin_amdgcn_rcpf(1.0f + er);
            float ez = exp2fast(__builtin_fmaf(acc[1][jt][0], NLOG2E, gc[1][jt]));
            float zz = __builtin_amdgcn_rcpf(1.0f + ez);
            // tanh(p) = 1 - 2/(1+exp2(2*log2e*p)); gc[2] holds 2*log2e*(gx+bih_n)
            float inner = acc[2][jt][0] + bhn[jt];
            float en = exp2fast(__builtin_fmaf(rr * inner, LOG2E2, gc[2][jt]));
            float nn = __builtin_fmaf(__builtin_amdgcn_rcpf(1.0f + en), -2.0f, 1.0f);
            float hnew = __builtin_fmaf(zz, hreg[jt] - nn, nn);
            hreg[jt] = hnew;
            hb[jt] = f2bf(hnew);
            hn[wbase + jt * 16] = hb[jt];
        }

        if (h1_out && quad == 0) {
            h1_out[hof]      = hb[0];
            h1_out[hof + 16] = hb[1];
        }
        hof += HID;

        if (hlast && t == SEQT - 1 && quad == 0) {
            hlast[(size_t)b0 * HID + j0]      = hreg[0];
            hlast[(size_t)b0 * HID + j0 + 16] = hreg[1];
        }

        // rotate prefetched gx into place
#pragma unroll
        for (int g3 = 0; g3 < 3; g3++) {
            gc[g3][0] = gcn[g3][0];
            gc[g3][1] = gcn[g3][1];
        }

        __syncthreads();
    }
}

// out[256,118] = hlast[256,256] @ fcW[118,256]^T + fcb
__global__ __launch_bounds__(128) void fc_kernel(
    const float* __restrict__ hlast, const float* __restrict__ W,
    const float* __restrict__ b, float* __restrict__ out)
{
    __shared__ float hsm[HID];
    int bidx = blockIdx.x;
    for (int i = threadIdx.x; i < HID; i += 128) hsm[i] = hlast[(size_t)bidx * HID + i];
    __syncthreads();
    int o = threadIdx.x;
    if (o < OUTD) {
        float acc = b[o];
        const float* wrow = W + (size_t)o * HID;
#pragma unroll 4
        for (int k = 0; k < HID; k++) acc += hsm[k] * wrow[k];
        out[(size_t)bidx * OUTD + o] = acc;
    }
}

extern "C" void kernel_launch(void* const* d_in, const int* in_sizes, int n_in,
                              void* d_out, int out_size, void* d_ws, size_t ws_size,
                              hipStream_t stream) {
    const float* x    = (const float*)d_in[0];
    const float* Wih0 = (const float*)d_in[1];
    const float* Whh0 = (const float*)d_in[2];
    const float* bih0 = (const float*)d_in[3];
    const float* bhh0 = (const float*)d_in[4];
    const float* Wih1 = (const float*)d_in[5];
    const float* Whh1 = (const float*)d_in[6];
    const float* bih1 = (const float*)d_in[7];
    const float* bhh1 = (const float*)d_in[8];
    const float* fcW  = (const float*)d_in[9];
    const float* fcb  = (const float*)d_in[10];
    float* out = (float*)d_out;

    char* ws = (char*)d_ws;
    size_t off = 0;
    auto walloc = [&](size_t bytes) {
        void* p = ws + off;
        off = (off + bytes + 255) & ~(size_t)255;
        return p;
    };

    const int M = BATCH * SEQT;                       // 51200
    // +16KB tail pad: gru_scan prefetches gx one step past the last row.
    float*          gxb  = (float*)         walloc((size_t)M * G3 * 4 + 16384);
    unsigned short* h1b  = (unsigned short*)walloc((size_t)M * HID * 2);  //  26.2 MB
    unsigned short* w0b  = (unsigned short*)walloc((size_t)W0SZ * 2);
    unsigned short* wh0b = (unsigned short*)walloc((size_t)WHSZ * 2);
    unsigned short* w1b  = (unsigned short*)walloc((size_t)WHSZ * 2);
    unsigned short* wh1b = (unsigned short*)walloc((size_t)WHSZ * 2);
    float*          bc0  = (float*)         walloc(G3 * 4);
    float*          bc1  = (float*)         walloc(G3 * 4);
    float*          hlast= (float*)         walloc((size_t)BATCH * HID * 4);

    // xb (13.1 MB, bf16 x) aliases h1b (26.2 MB): xb is dead before gru_scan
    // first writes h1b (gemm0 completes first on the same stream).
    unsigned short* xb = h1b;

    cvt_all    <<<2048, 256, 0, stream>>>(x, Wih0, Whh0, Wih1, Whh1,
                                          xb, w0b, wh0b, w1b, wh1b);
    combine_bias<<<6,   256, 0, stream>>>(bih0, bhh0, bih1, bhh1, bc0, bc1);

    // layer 0
    gemm_bn<IND><<<dim3(6, M / 128), 256, 0, stream>>>(xb, w0b, bc0, gxb);
    gru_scan<<<BATCH, 512, 0, stream>>>(gxb, wh0b, bhh0, h1b, nullptr);

    // layer 1
    gemm_bn<HID><<<dim3(6, M / 128), 256, 0, stream>>>(h1b, w1b, bc1, gxb);
    gru_scan<<<BATCH, 512, 0, stream>>>(gxb, wh1b, bhh1, nullptr, hlast);

    fc_kernel<<<BATCH, 128, 0, stream>>>(hlast, fcW, fcb, out);
}

// Round 7
// 569.391 us; speedup vs baseline: 1.0811x; 1.0811x over previous
//
#include <hip/hip_runtime.h>
#include <hip/hip_bf16.h>
#include <stdint.h>

// Problem constants
#define BATCH 256
#define SEQT  200
#define IND   128
#define HID   256
#define G3    768   // 3*HID
#define OUTD  118

#define TC    25    // steps per pipeline chunk
#define NC    8     // chunks (TC*NC == SEQT)

#define HSTRIDE 264  // h-state LDS row stride in shorts
#define W0SZ (G3*IND)
#define WHSZ (G3*HID)
#define XSZ  (BATCH*SEQT*IND)

#define SLOT_F  (BATCH*TC*G3)      // floats per gx ring slot (4,915,200)
#define SLOTP_F (SLOT_F + 1024)    // +4KB pad for tail prefetch

#define NLOG2E (-1.44269504f)
#define LOG2E2 2.88539008f

typedef short  short8 __attribute__((ext_vector_type(8)));
typedef float  f32x4  __attribute__((ext_vector_type(4)));
typedef int    i32x4  __attribute__((ext_vector_type(4)));

__device__ __forceinline__ float exp2fast(float x) {
#if __has_builtin(__builtin_amdgcn_exp2f)
    return __builtin_amdgcn_exp2f(x);
#else
    return exp2f(x);
#endif
}

__device__ __forceinline__ unsigned short f2bf(float x) {
    union { float f; uint32_t u; } v; v.f = x;
    uint32_t u = v.u;
    u += 0x7FFF + ((u >> 16) & 1);   // round-to-nearest-even
    return (unsigned short)(u >> 16);
}

// Fused float4-vectorized conversion: x + all four weight matrices.
__global__ void cvt_all(const float* __restrict__ x,
                        const float* __restrict__ w0,  const float* __restrict__ wh0,
                        const float* __restrict__ w1,  const float* __restrict__ wh1,
                        unsigned short* __restrict__ xb,
                        unsigned short* __restrict__ o0,  unsigned short* __restrict__ oh0,
                        unsigned short* __restrict__ o1,  unsigned short* __restrict__ oh1) {
    const int n4 = (XSZ + W0SZ + 3 * WHSZ) / 4;
    int idx = blockIdx.x * blockDim.x + threadIdx.x;
    int stride = gridDim.x * blockDim.x;
    for (int i = idx; i < n4; i += stride) {
        int j = i * 4;
        const float* src; unsigned short* dst;
        if (j < XSZ) { src = x; dst = xb; }
        else {
            j -= XSZ;
            if (j < W0SZ) { src = w0; dst = o0; }
            else {
                j -= W0SZ;
                if (j < WHSZ) { src = wh0; dst = oh0; }
                else {
                    j -= WHSZ;
                    if (j < WHSZ) { src = w1; dst = o1; }
                    else { j -= WHSZ; src = wh1; dst = oh1; }
                }
            }
        }
        float4 v = *(const float4*)(src + j);
        ushort4 o;
        o.x = f2bf(v.x); o.y = f2bf(v.y); o.z = f2bf(v.z); o.w = f2bf(v.w);
        *(ushort4*)(dst + j) = o;
    }
}

__global__ void combine_bias(const float* __restrict__ bih0, const float* __restrict__ bhh0,
                             const float* __restrict__ bih1, const float* __restrict__ bhh1,
                             float* __restrict__ bc0, float* __restrict__ bc1) {
    int i = blockIdx.x * blockDim.x + threadIdx.x;
    if (i < G3) bc0[i] = bih0[i] + (i < 2 * HID ? bhh0[i] : 0.0f);
    else if (i < 2 * G3) {
        int j = i - G3;
        bc1[j] = bih1[j] + (j < 2 * HID ? bhh1[j] : 0.0f);
    }
}

// ---- gemm unit (256 threads), chunk-rows [b][lt] layout in C slot ----
// Stage A panel into LDS (coalesced 16B/lane; chunk-row -> (b,lt) via /25).
template<int K>
__device__ __forceinline__ void g_stage(i32x4* sA, int tile, int t0,
    const unsigned short* A, const unsigned short* Bt, const float* bias,
    int tidu, short8 (&b)[2][8], float& bia0, float& bia1, int& g0o)
{
    constexpr int KS = K / 32, CPR = K / 8, LSTR = CPR + 1, PT = 128 * CPR / 256;
    const int wave = tidu >> 6, lane = tidu & 63, col = lane & 15, quad = lane >> 4;
    const int nb = tile % 6, panel = tile / 6;
    const int g0 = nb * 128 + wave * 32 + col;
    g0o = g0;
#pragma unroll
    for (int jt = 0; jt < 2; jt++)
#pragma unroll
        for (int ks = 0; ks < KS; ks++)
            b[jt][ks] = *(const short8*)(Bt + (size_t)(g0 + jt * 16) * K + ks * 32 + quad * 8);
    bia0 = bias[g0]; bia1 = bias[g0 + 16];

    i32x4 st[PT];
#pragma unroll
    for (int i = 0; i < PT; i++) {
        int g = i * 256 + tidu;
        int row = g / CPR, cc = g % CPR;
        int r = panel * 128 + row;
        int bb = r / TC, lt = r - bb * TC;
        st[i] = *(const i32x4*)(A + (size_t)(bb * SEQT + t0 + lt) * K + cc * 8);
    }
#pragma unroll
    for (int i = 0; i < PT; i++) {
        int g = i * 256 + tidu;
        sA[(g / CPR) * LSTR + (g % CPR)] = st[i];
    }
}

template<int K>
__device__ __forceinline__ void g_comp(const i32x4* sA, int tile,
    const short8 (&b)[2][8], float bia0, float bia1, int g0,
    float* Cslot, int tidu)
{
    constexpr int KS = K / 32, CPR = K / 8, LSTR = CPR + 1;
    const int lane = tidu & 63, col = lane & 15, quad = lane >> 4;
    const int nb = tile % 6, panel = tile / 6;
    const float scl = (nb < 4) ? NLOG2E : LOG2E2;
#pragma unroll 2
    for (int ms = 0; ms < 8; ms++) {
        f32x4 a0 = (f32x4)(0.0f), a1 = (f32x4)(0.0f);
#pragma unroll
        for (int ks = 0; ks < KS; ks++) {
            short8 a = __builtin_bit_cast(short8, sA[(ms * 16 + col) * LSTR + ks * 4 + quad]);
            a0 = __builtin_amdgcn_mfma_f32_16x16x32_bf16(a, b[0][ks], a0, 0, 0, 0);
            a1 = __builtin_amdgcn_mfma_f32_16x16x32_bf16(a, b[1][ks], a1, 0, 0, 0);
        }
        float* crow = Cslot + (size_t)(panel * 128 + ms * 16 + quad * 4) * G3 + g0;
#pragma unroll
        for (int r = 0; r < 4; r++) {
            crow[(size_t)r * G3]      = (a0[r] + bia0) * scl;
            crow[(size_t)r * G3 + 16] = (a1[r] + bia1) * scl;
        }
    }
}

// ---- pipelined mega-kernel ----
// Launch c runs: blocks [0,32)  scan0 chunk c-1  (32 WGs x 8 batches)
//                blocks [32,64) scan1 chunk c-3
//                blocks [64,256) gemm units: gemm0 chunk c, gemm1 chunk c-2
// All cross-stage deps are satisfied by prior launches (stream order).
__global__ __launch_bounds__(512, 2) void pipe(
    int c,
    const unsigned short* xb,
    unsigned short* h1b,                      // scan0 writes; gemm1 reads (older chunk)
    const unsigned short* w0b, const unsigned short* w1b,
    const float* bc0, const float* bc1,
    float* gx0, float* gx1,                   // 2-slot rings, [b][TC][G3] per slot
    const unsigned short* wh0, const unsigned short* wh1,
    const float* bhh0, const float* bhh1,
    float* hst0, float* hst1)                 // fp32 h-state [B][HID]
{
    __shared__ __attribute__((aligned(16))) char SM[16896 + 135168];

    const int bid = blockIdx.x;
    const int tid = threadIdx.x;

    if (bid < 64) {
        // ================= scan role =================
        const bool L0 = bid < 32;
        const int cs = L0 ? c - 1 : c - 3;
        if (cs < 0 || cs >= NC) return;
        const float* gxslot = (L0 ? gx0 : gx1) + (size_t)(cs & 1) * SLOTP_F;
        const unsigned short* Whh = L0 ? wh0 : wh1;
        const float* bhh = L0 ? bhh0 : bhh1;
        float* hstate = L0 ? hst0 : hst1;
        unsigned short* h1o = L0 ? h1b : nullptr;
        const int wg = L0 ? bid : bid - 32;

        unsigned short* hs  = (unsigned short*)SM;            // [2][16*HSTRIDE]
        unsigned short* wn1 = (unsigned short*)(SM + 16896);  // [8*4096] n-gate jt1

        const int wave = tid >> 6, lane = tid & 63;
        const int col = lane & 15, quad = lane >> 4;
        const int jbase = wave * 32, j0 = jbase + col, j1 = jbase + 16 + col;
        const int b0 = wg * 8;
        const int bA = b0 + 2 * quad, bB = bA + 1;   // batches at MFMA rows quad*4, quad*4+2
        const int rowA = quad * 4, rowB = quad * 4 + 2;

        // r,z weights (both jt) -> 128 pinned VGPRs
        i32x4 wrz[2][2][8];
#pragma unroll
        for (int g = 0; g < 2; g++)
#pragma unroll
            for (int jt = 0; jt < 2; jt++)
#pragma unroll
                for (int ks = 0; ks < 8; ks++)
                    wrz[g][jt][ks] = *(const i32x4*)(
                        Whh + (size_t)(g * HID + jbase + jt * 16 + col) * HID + ks * 32 + quad * 8);
        // n-gate jt0 -> 32 pinned VGPRs
        i32x4 wn0[8];
#pragma unroll
        for (int ks = 0; ks < 8; ks++)
            wn0[ks] = *(const i32x4*)(
                Whh + (size_t)(2 * HID + j0) * HID + ks * 32 + quad * 8);
        // n-gate jt1 -> LDS (lane-contiguous fragment order, conflict-free)
        const int wnb = wave * 4096 + lane * 8;
#pragma unroll
        for (int ks = 0; ks < 8; ks++)
            *(short8*)&wn1[wnb + ks * 512] =
                *(const short8*)(Whh + (size_t)(2 * HID + j1) * HID + ks * 32 + quad * 8);

        // zero both h buffers (odd rows = MFMA padding stay zero)
        for (int i = tid; i < 2 * 16 * HSTRIDE; i += 512) hs[i] = 0;

        float hreg[2][2];   // [bsel][jt], fp32 carried state
        if (cs == 0) {
            hreg[0][0] = hreg[0][1] = hreg[1][0] = hreg[1][1] = 0.0f;
        } else {
            hreg[0][0] = hstate[bA * HID + j0];
            hreg[0][1] = hstate[bA * HID + j1];
            hreg[1][0] = hstate[bB * HID + j0];
            hreg[1][1] = hstate[bB * HID + j1];
        }
        float bhn[2] = { bhh[2 * HID + j0], bhh[2 * HID + j1] };

        __syncthreads();   // zeroing done
        // seed live rows of hs[0] with bf16(state) — identical to monolithic LDS content
        hs[rowA * HSTRIDE + j0] = f2bf(hreg[0][0]);
        hs[rowA * HSTRIDE + j1] = f2bf(hreg[0][1]);
        hs[rowB * HSTRIDE + j0] = f2bf(hreg[1][0]);
        hs[rowB * HSTRIDE + j1] = f2bf(hreg[1][1]);
        __syncthreads();

        int gofA = (bA * TC) * G3 + j0;
        int gofB = (bB * TC) * G3 + j0;
        int hofA = (bA * SEQT + cs * TC) * HID + j0;
        int hofB = (bB * SEQT + cs * TC) * HID + j0;
        const int abase = col * HSTRIDE + quad * 8;

        // preload gx for lt=0
        float gc[3][2][2];   // [gate][jt][bsel]
#pragma unroll
        for (int g3 = 0; g3 < 3; g3++)
#pragma unroll
            for (int jt = 0; jt < 2; jt++) {
                gc[g3][jt][0] = gxslot[gofA + g3 * HID + jt * 16];
                gc[g3][jt][1] = gxslot[gofB + g3 * HID + jt * 16];
            }
        gofA += G3; gofB += G3;

        for (int lt = 0; lt < TC; lt++) {
            unsigned short* hc = hs + (lt & 1) * 16 * HSTRIDE;
            unsigned short* hn = hs + ((lt & 1) ^ 1) * 16 * HSTRIDE;

            // pin weight regs
#pragma unroll
            for (int g = 0; g < 2; g++)
#pragma unroll
                for (int jt = 0; jt < 2; jt++)
#pragma unroll
                    for (int ks = 0; ks < 8; ks++)
                        asm volatile("" : "+v"(wrz[g][jt][ks]));
#pragma unroll
            for (int ks = 0; ks < 8; ks++)
                asm volatile("" : "+v"(wn0[ks]));

            // prefetch gx for lt+1 (slot tail-padded; last prefetch discarded)
            float gcn[3][2][2];
#pragma unroll
            for (int g3 = 0; g3 < 3; g3++)
#pragma unroll
                for (int jt = 0; jt < 2; jt++) {
                    gcn[g3][jt][0] = gxslot[gofA + g3 * HID + jt * 16];
                    gcn[g3][jt][1] = gxslot[gofB + g3 * HID + jt * 16];
                }
            gofA += G3; gofB += G3;

            f32x4 acc[3][2];
#pragma unroll
            for (int g = 0; g < 3; g++)
#pragma unroll
                for (int jt = 0; jt < 2; jt++) acc[g][jt] = (f32x4)(0.0f);

            __builtin_amdgcn_s_setprio(1);
#pragma unroll
            for (int ks = 0; ks < 8; ks++) {
                short8 a = *(const short8*)(&hc[abase + ks * 32]);
                acc[0][0] = __builtin_amdgcn_mfma_f32_16x16x32_bf16(a, __builtin_bit_cast(short8, wrz[0][0][ks]), acc[0][0], 0, 0, 0);
                acc[0][1] = __builtin_amdgcn_mfma_f32_16x16x32_bf16(a, __builtin_bit_cast(short8, wrz[0][1][ks]), acc[0][1], 0, 0, 0);
                acc[1][0] = __builtin_amdgcn_mfma_f32_16x16x32_bf16(a, __builtin_bit_cast(short8, wrz[1][0][ks]), acc[1][0], 0, 0, 0);
                acc[1][1] = __builtin_amdgcn_mfma_f32_16x16x32_bf16(a, __builtin_bit_cast(short8, wrz[1][1][ks]), acc[1][1], 0, 0, 0);
                acc[2][0] = __builtin_amdgcn_mfma_f32_16x16x32_bf16(a, __builtin_bit_cast(short8, wn0[ks]),       acc[2][0], 0, 0, 0);
                short8 b1 = *(const short8*)&wn1[wnb + ks * 512];
                acc[2][1] = __builtin_amdgcn_mfma_f32_16x16x32_bf16(a, b1, acc[2][1], 0, 0, 0);
            }
            __builtin_amdgcn_s_setprio(0);

            unsigned short hb[2][2];
#pragma unroll
            for (int bs = 0; bs < 2; bs++)
#pragma unroll
                for (int jt = 0; jt < 2; jt++) {
                    const int r = bs * 2;   // acc row: rowA -> 0, rowB -> 2
                    float er = exp2fast(__builtin_fmaf(acc[0][jt][r], NLOG2E, gc[0][jt][bs]));
                    float rr = __builtin_amdgcn_rcpf(1.0f + er);
                    float ez = exp2fast(__builtin_fmaf(acc[1][jt][r], NLOG2E, gc[1][jt][bs]));
                    float zz = __builtin_amdgcn_rcpf(1.0f + ez);
                    float inner = acc[2][jt][r] + bhn[jt];
                    float en = exp2fast(__builtin_fmaf(rr * inner, LOG2E2, gc[2][jt][bs]));
                    float nn = __builtin_fmaf(__builtin_amdgcn_rcpf(1.0f + en), -2.0f, 1.0f);
                    float hnew = __builtin_fmaf(zz, hreg[bs][jt] - nn, nn);
                    hreg[bs][jt] = hnew;
                    hb[bs][jt] = f2bf(hnew);
                    hn[(bs ? rowB : rowA) * HSTRIDE + j0 + jt * 16] = hb[bs][jt];
                }

            if (h1o) {
                h1o[hofA]      = hb[0][0];
                h1o[hofA + 16] = hb[0][1];
                h1o[hofB]      = hb[1][0];
                h1o[hofB + 16] = hb[1][1];
            }
            hofA += HID; hofB += HID;

#pragma unroll
            for (int g3 = 0; g3 < 3; g3++)
#pragma unroll
                for (int jt = 0; jt < 2; jt++) {
                    gc[g3][jt][0] = gcn[g3][jt][0];
                    gc[g3][jt][1] = gcn[g3][jt][1];
                }

            __syncthreads();
        }

        // persist fp32 state for next chunk (hst1 of last chunk == hlast for fc)
        hstate[bA * HID + j0] = hreg[0][0];
        hstate[bA * HID + j1] = hreg[0][1];
        hstate[bB * HID + j0] = hreg[1][0];
        hstate[bB * HID + j1] = hreg[1][1];

    } else {
        // ================= gemm role =================
        const int cg0 = c, cg1 = c - 2;
        const int G0t = (cg0 < NC) ? 300 : 0;
        const int G1t = (cg1 >= 0 && cg1 < NC) ? 300 : 0;
        if (G0t + G1t == 0) return;

        i32x4* sA = (i32x4*)(SM + 16896) + (tid >> 8) * 4224;
        const int u    = (bid - 64) * 2 + (tid >> 8);   // unit id [0,384)
        const int tidu = tid & 255;
        float* c0slot = gx0 + (size_t)(cg0 & 1) * SLOTP_F;
        float* c1slot = gx1 + (size_t)(cg1 & 1) * SLOTP_F;

        short8 bf[2][8];
        float bia0, bia1; int g0c;

#pragma unroll 1
        for (int it = 0; it < 2; it++) {
            int t = u + it * 384;
            int mode = (t < G0t) ? 0 : ((t - G0t < G1t) ? 1 : -1);
            int tile = (mode == 1) ? t - G0t : t;
            if (mode == 0)
                g_stage<IND>(sA, tile, cg0 * TC, xb, w0b, bc0, tidu, bf, bia0, bia1, g0c);
            else if (mode == 1)
                g_stage<HID>(sA, tile, cg1 * TC, h1b, w1b, bc1, tidu, bf, bia0, bia1, g0c);
            __syncthreads();
            if (mode == 0)
                g_comp<IND>(sA, tile, bf, bia0, bia1, g0c, c0slot, tidu);
            else if (mode == 1)
                g_comp<HID>(sA, tile, bf, bia0, bia1, g0c, c1slot, tidu);
            __syncthreads();
        }
    }
}

// out[256,118] = hlast[256,256] @ fcW[118,256]^T + fcb
__global__ __launch_bounds__(128) void fc_kernel(
    const float* __restrict__ hlast, const float* __restrict__ W,
    const float* __restrict__ b, float* __restrict__ out)
{
    __shared__ float hsm[HID];
    int bidx = blockIdx.x;
    for (int i = threadIdx.x; i < HID; i += 128) hsm[i] = hlast[(size_t)bidx * HID + i];
    __syncthreads();
    int o = threadIdx.x;
    if (o < OUTD) {
        float acc = b[o];
        const float* wrow = W + (size_t)o * HID;
#pragma unroll 4
        for (int k = 0; k < HID; k++) acc += hsm[k] * wrow[k];
        out[(size_t)bidx * OUTD + o] = acc;
    }
}

extern "C" void kernel_launch(void* const* d_in, const int* in_sizes, int n_in,
                              void* d_out, int out_size, void* d_ws, size_t ws_size,
                              hipStream_t stream) {
    const float* x    = (const float*)d_in[0];
    const float* Wih0 = (const float*)d_in[1];
    const float* Whh0 = (const float*)d_in[2];
    const float* bih0 = (const float*)d_in[3];
    const float* bhh0 = (const float*)d_in[4];
    const float* Wih1 = (const float*)d_in[5];
    const float* Whh1 = (const float*)d_in[6];
    const float* bih1 = (const float*)d_in[7];
    const float* bhh1 = (const float*)d_in[8];
    const float* fcW  = (const float*)d_in[9];
    const float* fcb  = (const float*)d_in[10];
    float* out = (float*)d_out;

    char* ws = (char*)d_ws;
    size_t off = 0;
    auto walloc = [&](size_t bytes) {
        void* p = ws + off;
        off = (off + bytes + 255) & ~(size_t)255;
        return p;
    };

    const int M = BATCH * SEQT;                       // 51200
    unsigned short* xb   = (unsigned short*)walloc((size_t)XSZ * 2);        // 13.1 MB
    float*          gx0  = (float*)         walloc((size_t)2 * SLOTP_F * 4); // 39.3 MB
    float*          gx1  = (float*)         walloc((size_t)2 * SLOTP_F * 4); // 39.3 MB
    unsigned short* h1b  = (unsigned short*)walloc((size_t)M * HID * 2);    // 26.2 MB
    unsigned short* w0b  = (unsigned short*)walloc((size_t)W0SZ * 2);
    unsigned short* wh0b = (unsigned short*)walloc((size_t)WHSZ * 2);
    unsigned short* w1b  = (unsigned short*)walloc((size_t)WHSZ * 2);
    unsigned short* wh1b = (unsigned short*)walloc((size_t)WHSZ * 2);
    float*          bc0  = (float*)         walloc(G3 * 4);
    float*          bc1  = (float*)         walloc(G3 * 4);
    float*          hst0 = (float*)         walloc((size_t)BATCH * HID * 4);
    float*          hst1 = (float*)         walloc((size_t)BATCH * HID * 4);

    cvt_all     <<<2048, 256, 0, stream>>>(x, Wih0, Whh0, Wih1, Whh1,
                                           xb, w0b, wh0b, w1b, wh1b);
    combine_bias<<<6,    256, 0, stream>>>(bih0, bhh0, bih1, bhh1, bc0, bc1);

    // pipeline: launch c = { gemm0(c) | scan0(c-1) | gemm1(c-2) | scan1(c-3) }
    for (int c = 0; c <= NC + 2; ++c)
        pipe<<<256, 512, 0, stream>>>(c, xb, h1b, w0b, w1b, bc0, bc1,
                                      gx0, gx1, wh0b, wh1b, bhh0, bhh1, hst0, hst1);

    fc_kernel<<<BATCH, 128, 0, stream>>>(hst1, fcW, fcb, out);
}

// Round 8
// 501.964 us; speedup vs baseline: 1.2263x; 1.1343x over previous
//
#include <hip/hip_runtime.h>
#include <hip/hip_bf16.h>
#include <stdint.h>

// Problem constants
#define BATCH 256
#define SEQT  200
#define IND   128
#define HID   256
#define G3    768   // 3*HID
#define OUTD  118

#define TC    25    // steps per pipeline chunk
#define NC    8     // chunks (TC*NC == SEQT)

#define HSTRIDE 264  // h-state LDS row stride in shorts
#define W0SZ (G3*IND)
#define WHSZ (G3*HID)
#define XSZ  (BATCH*SEQT*IND)

#define SLOT_F  (BATCH*TC*G3)      // floats per gx ring slot (4,915,200)
#define SLOTP_F (SLOT_F + 1024)    // +4KB pad for tail prefetch

#define NLOG2E (-1.44269504f)
#define LOG2E2 2.88539008f

typedef short  short8 __attribute__((ext_vector_type(8)));
typedef float  f32x4  __attribute__((ext_vector_type(4)));
typedef int    i32x4  __attribute__((ext_vector_type(4)));

__device__ __forceinline__ float exp2fast(float x) {
#if __has_builtin(__builtin_amdgcn_exp2f)
    return __builtin_amdgcn_exp2f(x);
#else
    return exp2f(x);
#endif
}

__device__ __forceinline__ unsigned short f2bf(float x) {
    union { float f; uint32_t u; } v; v.f = x;
    uint32_t u = v.u;
    u += 0x7FFF + ((u >> 16) & 1);   // round-to-nearest-even
    return (unsigned short)(u >> 16);
}

// Fused float4-vectorized conversion: x + all four weight matrices.
__global__ void cvt_all(const float* __restrict__ x,
                        const float* __restrict__ w0,  const float* __restrict__ wh0,
                        const float* __restrict__ w1,  const float* __restrict__ wh1,
                        unsigned short* __restrict__ xb,
                        unsigned short* __restrict__ o0,  unsigned short* __restrict__ oh0,
                        unsigned short* __restrict__ o1,  unsigned short* __restrict__ oh1) {
    const int n4 = (XSZ + W0SZ + 3 * WHSZ) / 4;
    int idx = blockIdx.x * blockDim.x + threadIdx.x;
    int stride = gridDim.x * blockDim.x;
    for (int i = idx; i < n4; i += stride) {
        int j = i * 4;
        const float* src; unsigned short* dst;
        if (j < XSZ) { src = x; dst = xb; }
        else {
            j -= XSZ;
            if (j < W0SZ) { src = w0; dst = o0; }
            else {
                j -= W0SZ;
                if (j < WHSZ) { src = wh0; dst = oh0; }
                else {
                    j -= WHSZ;
                    if (j < WHSZ) { src = w1; dst = o1; }
                    else { j -= WHSZ; src = wh1; dst = oh1; }
                }
            }
        }
        float4 v = *(const float4*)(src + j);
        ushort4 o;
        o.x = f2bf(v.x); o.y = f2bf(v.y); o.z = f2bf(v.z); o.w = f2bf(v.w);
        *(ushort4*)(dst + j) = o;
    }
}

__global__ void combine_bias(const float* __restrict__ bih0, const float* __restrict__ bhh0,
                             const float* __restrict__ bih1, const float* __restrict__ bhh1,
                             float* __restrict__ bc0, float* __restrict__ bc1) {
    int i = blockIdx.x * blockDim.x + threadIdx.x;
    if (i < G3) bc0[i] = bih0[i] + (i < 2 * HID ? bhh0[i] : 0.0f);
    else if (i < 2 * G3) {
        int j = i - G3;
        bc1[j] = bih1[j] + (j < 2 * HID ? bhh1[j] : 0.0f);
    }
}

// ---- gemm unit (256 threads), chunk-rows [b][lt] layout in C slot ----
template<int K>
__device__ __forceinline__ void g_stage(i32x4* sA, int tile, int t0,
    const unsigned short* A, const unsigned short* Bt, const float* bias,
    int tidu, short8 (&b)[2][8], float& bia0, float& bia1, int& g0o)
{
    constexpr int KS = K / 32, CPR = K / 8, LSTR = CPR + 1, PT = 128 * CPR / 256;
    const int wave = tidu >> 6, lane = tidu & 63, col = lane & 15, quad = lane >> 4;
    const int nb = tile % 6, panel = tile / 6;
    const int g0 = nb * 128 + wave * 32 + col;
    g0o = g0;
#pragma unroll
    for (int jt = 0; jt < 2; jt++)
#pragma unroll
        for (int ks = 0; ks < KS; ks++)
            b[jt][ks] = *(const short8*)(Bt + (size_t)(g0 + jt * 16) * K + ks * 32 + quad * 8);
    bia0 = bias[g0]; bia1 = bias[g0 + 16];

    i32x4 st[PT];
#pragma unroll
    for (int i = 0; i < PT; i++) {
        int g = i * 256 + tidu;
        int row = g / CPR, cc = g % CPR;
        int r = panel * 128 + row;
        int bb = r / TC, lt = r - bb * TC;
        st[i] = *(const i32x4*)(A + (size_t)(bb * SEQT + t0 + lt) * K + cc * 8);
    }
#pragma unroll
    for (int i = 0; i < PT; i++) {
        int g = i * 256 + tidu;
        sA[(g / CPR) * LSTR + (g % CPR)] = st[i];
    }
}

template<int K>
__device__ __forceinline__ void g_comp(const i32x4* sA, int tile,
    const short8 (&b)[2][8], float bia0, float bia1, int g0,
    float* Cslot, int tidu)
{
    constexpr int KS = K / 32, CPR = K / 8, LSTR = CPR + 1;
    const int lane = tidu & 63, col = lane & 15, quad = lane >> 4;
    const int nb = tile % 6, panel = tile / 6;
    const float scl = (nb < 4) ? NLOG2E : LOG2E2;
#pragma unroll 2
    for (int ms = 0; ms < 8; ms++) {
        f32x4 a0 = (f32x4)(0.0f), a1 = (f32x4)(0.0f);
#pragma unroll
        for (int ks = 0; ks < KS; ks++) {
            short8 a = __builtin_bit_cast(short8, sA[(ms * 16 + col) * LSTR + ks * 4 + quad]);
            a0 = __builtin_amdgcn_mfma_f32_16x16x32_bf16(a, b[0][ks], a0, 0, 0, 0);
            a1 = __builtin_amdgcn_mfma_f32_16x16x32_bf16(a, b[1][ks], a1, 0, 0, 0);
        }
        float* crow = Cslot + (size_t)(panel * 128 + ms * 16 + quad * 4) * G3 + g0;
#pragma unroll
        for (int r = 0; r < 4; r++) {
            crow[(size_t)r * G3]      = (a0[r] + bia0) * scl;
            crow[(size_t)r * G3 + 16] = (a1[r] + bia1) * scl;
        }
    }
}

// ---- pipelined mega-kernel ----
// Launch c: blocks [0,64)    scan0 chunk c-1  (64 WGs x 4 batches, R5 geometry)
//           blocks [64,128)  scan1 chunk c-3
//           blocks [128,256) gemm units (x2 per block, 3 iters): gemm0(c), gemm1(c-2)
// All cross-stage deps satisfied by stream-ordered prior launches.
__global__ __launch_bounds__(512, 2) void pipe(
    int c,
    const unsigned short* xb,
    unsigned short* h1b,
    const unsigned short* w0b, const unsigned short* w1b,
    const float* bc0, const float* bc1,
    float* gx0, float* gx1,                   // 2-slot rings, [b][TC][G3] per slot
    const unsigned short* wh0, const unsigned short* wh1,
    const float* bhh0, const float* bhh1,
    float* hst0, float* hst1)                 // fp32 h-state [B][HID]
{
    __shared__ __attribute__((aligned(16))) char SM[16896 + 135168];

    const int bid = blockIdx.x;
    const int tid = threadIdx.x;

    if (bid < 128) {
        // ================= scan role (R5 geometry: 4 batches/WG) =================
        const bool L0 = bid < 64;
        const int cs = L0 ? c - 1 : c - 3;
        if (cs < 0 || cs >= NC) return;
        const float* gxslot = (L0 ? gx0 : gx1) + (size_t)(cs & 1) * SLOTP_F;
        const unsigned short* Whh = L0 ? wh0 : wh1;
        const float* bhh = L0 ? bhh0 : bhh1;
        float* hstate = L0 ? hst0 : hst1;
        unsigned short* h1o = L0 ? h1b : nullptr;
        const int wg = L0 ? bid : bid - 64;

        unsigned short* hs = (unsigned short*)SM;   // [2][16*HSTRIDE]

        const int wave = tid >> 6, lane = tid & 63;
        const int col = lane & 15, quad = lane >> 4;
        const int jbase = wave * 32, j0 = jbase + col, j1 = jbase + 16 + col;
        const int bq  = wg * 4 + quad;        // this lane's batch
        const int row = quad * 4;             // its live MFMA row

        // r,z weights (both jt) -> 128 pinned VGPRs
        i32x4 wrz[2][2][8];
#pragma unroll
        for (int g = 0; g < 2; g++)
#pragma unroll
            for (int jt = 0; jt < 2; jt++)
#pragma unroll
                for (int ks = 0; ks < 8; ks++)
                    wrz[g][jt][ks] = *(const i32x4*)(
                        Whh + (size_t)(g * HID + jbase + jt * 16 + col) * HID + ks * 32 + quad * 8);
        // n-gate jt0 / jt1 -> 64 pinned VGPRs
        i32x4 wn0[8], wn1r[8];
#pragma unroll
        for (int ks = 0; ks < 8; ks++) {
            wn0[ks]  = *(const i32x4*)(Whh + (size_t)(2 * HID + j0) * HID + ks * 32 + quad * 8);
            wn1r[ks] = *(const i32x4*)(Whh + (size_t)(2 * HID + j1) * HID + ks * 32 + quad * 8);
        }

        // zero both h buffers (rows != 0 mod 4 stay zero: MFMA padding)
        for (int i = tid; i < 2 * 16 * HSTRIDE; i += 512) hs[i] = 0;

        float hreg[2];
        if (cs == 0) { hreg[0] = 0.0f; hreg[1] = 0.0f; }
        else {
            hreg[0] = hstate[bq * HID + j0];
            hreg[1] = hstate[bq * HID + j1];
        }
        float bhn[2] = { bhh[2 * HID + j0], bhh[2 * HID + j1] };

        __syncthreads();
        // seed live rows of buffer 0 with bf16(state) == monolithic LDS content
        hs[row * HSTRIDE + j0] = f2bf(hreg[0]);
        hs[row * HSTRIDE + j1] = f2bf(hreg[1]);
        __syncthreads();

        int gof = (bq * TC) * G3 + j0;
        int hof = (bq * SEQT + cs * TC) * HID + j0;
        const int abase = col * HSTRIDE + quad * 8;
        const int wbase = row * HSTRIDE + j0;

        // preload gx for lt=0
        float gc[3][2];
#pragma unroll
        for (int g3 = 0; g3 < 3; g3++) {
            gc[g3][0] = gxslot[gof + g3 * HID];
            gc[g3][1] = gxslot[gof + g3 * HID + 16];
        }
        gof += G3;

        for (int lt = 0; lt < TC; lt++) {
            unsigned short* hc = hs + (lt & 1) * 16 * HSTRIDE;
            unsigned short* hn = hs + ((lt & 1) ^ 1) * 16 * HSTRIDE;

            // pin weight regs: opaque per-iter redefinition blocks remat/sinking
#pragma unroll
            for (int g = 0; g < 2; g++)
#pragma unroll
                for (int jt = 0; jt < 2; jt++)
#pragma unroll
                    for (int ks = 0; ks < 8; ks++)
                        asm volatile("" : "+v"(wrz[g][jt][ks]));
#pragma unroll
            for (int ks = 0; ks < 8; ks++) {
                asm volatile("" : "+v"(wn0[ks]));
                asm volatile("" : "+v"(wn1r[ks]));
            }

            // prefetch gx for lt+1 (slot tail-padded; last prefetch discarded)
            float gcn[3][2];
#pragma unroll
            for (int g3 = 0; g3 < 3; g3++) {
                gcn[g3][0] = gxslot[gof + g3 * HID];
                gcn[g3][1] = gxslot[gof + g3 * HID + 16];
            }
            gof += G3;

            f32x4 acc[3][2];
#pragma unroll
            for (int g = 0; g < 3; g++)
#pragma unroll
                for (int jt = 0; jt < 2; jt++) acc[g][jt] = (f32x4)(0.0f);

            __builtin_amdgcn_s_setprio(1);
#pragma unroll
            for (int ks = 0; ks < 8; ks++) {
                short8 a = *(const short8*)(&hc[abase + ks * 32]);
                acc[0][0] = __builtin_amdgcn_mfma_f32_16x16x32_bf16(a, __builtin_bit_cast(short8, wrz[0][0][ks]), acc[0][0], 0, 0, 0);
                acc[0][1] = __builtin_amdgcn_mfma_f32_16x16x32_bf16(a, __builtin_bit_cast(short8, wrz[0][1][ks]), acc[0][1], 0, 0, 0);
                acc[1][0] = __builtin_amdgcn_mfma_f32_16x16x32_bf16(a, __builtin_bit_cast(short8, wrz[1][0][ks]), acc[1][0], 0, 0, 0);
                acc[1][1] = __builtin_amdgcn_mfma_f32_16x16x32_bf16(a, __builtin_bit_cast(short8, wrz[1][1][ks]), acc[1][1], 0, 0, 0);
                acc[2][0] = __builtin_amdgcn_mfma_f32_16x16x32_bf16(a, __builtin_bit_cast(short8, wn0[ks]),       acc[2][0], 0, 0, 0);
                acc[2][1] = __builtin_amdgcn_mfma_f32_16x16x32_bf16(a, __builtin_bit_cast(short8, wn1r[ks]),      acc[2][1], 0, 0, 0);
            }
            __builtin_amdgcn_s_setprio(0);

            unsigned short hb[2];
#pragma unroll
            for (int jt = 0; jt < 2; jt++) {
                float er = exp2fast(__builtin_fmaf(acc[0][jt][0], NLOG2E, gc[0][jt]));
                float rr = __builtin_amdgcn_rcpf(1.0f + er);
                float ez = exp2fast(__builtin_fmaf(acc[1][jt][0], NLOG2E, gc[1][jt]));
                float zz = __builtin_amdgcn_rcpf(1.0f + ez);
                float inner = acc[2][jt][0] + bhn[jt];
                float en = exp2fast(__builtin_fmaf(rr * inner, LOG2E2, gc[2][jt]));
                float nn = __builtin_fmaf(__builtin_amdgcn_rcpf(1.0f + en), -2.0f, 1.0f);
                float hnew = __builtin_fmaf(zz, hreg[jt] - nn, nn);
                hreg[jt] = hnew;
                hb[jt] = f2bf(hnew);
                hn[wbase + jt * 16] = hb[jt];
            }

            if (h1o) {
                h1o[hof]      = hb[0];
                h1o[hof + 16] = hb[1];
            }
            hof += HID;

#pragma unroll
            for (int g3 = 0; g3 < 3; g3++) {
                gc[g3][0] = gcn[g3][0];
                gc[g3][1] = gcn[g3][1];
            }

            __syncthreads();
        }

        // persist fp32 state for next chunk (hst1 after last chunk == fc input)
        hstate[bq * HID + j0] = hreg[0];
        hstate[bq * HID + j1] = hreg[1];

    } else {
        // ================= gemm role =================
        const int cg0 = c, cg1 = c - 2;
        const int G0t = (cg0 < NC) ? 300 : 0;
        const int G1t = (cg1 >= 0 && cg1 < NC) ? 300 : 0;
        if (G0t + G1t == 0) return;

        i32x4* sA = (i32x4*)(SM + 16896) + (tid >> 8) * 4224;
        const int u    = (bid - 128) * 2 + (tid >> 8);   // unit id [0,256)
        const int tidu = tid & 255;
        float* c0slot = gx0 + (size_t)(cg0 & 1) * SLOTP_F;
        float* c1slot = gx1 + (size_t)(cg1 & 1) * SLOTP_F;

        short8 bf[2][8];
        float bia0, bia1; int g0c;

#pragma unroll 1
        for (int it = 0; it < 3; it++) {
            int t = it * 256 + u;
            int mode = (t < G0t) ? 0 : ((t - G0t < G1t) ? 1 : -1);
            int tile = (mode == 1) ? t - G0t : t;
            if (mode == 0)
                g_stage<IND>(sA, tile, cg0 * TC, xb, w0b, bc0, tidu, bf, bia0, bia1, g0c);
            else if (mode == 1)
                g_stage<HID>(sA, tile, cg1 * TC, h1b, w1b, bc1, tidu, bf, bia0, bia1, g0c);
            __syncthreads();
            if (mode == 0)
                g_comp<IND>(sA, tile, bf, bia0, bia1, g0c, c0slot, tidu);
            else if (mode == 1)
                g_comp<HID>(sA, tile, bf, bia0, bia1, g0c, c1slot, tidu);
            __syncthreads();
        }
    }
}

// out[256,118] = hlast[256,256] @ fcW[118,256]^T + fcb
__global__ __launch_bounds__(128) void fc_kernel(
    const float* __restrict__ hlast, const float* __restrict__ W,
    const float* __restrict__ b, float* __restrict__ out)
{
    __shared__ float hsm[HID];
    int bidx = blockIdx.x;
    for (int i = threadIdx.x; i < HID; i += 128) hsm[i] = hlast[(size_t)bidx * HID + i];
    __syncthreads();
    int o = threadIdx.x;
    if (o < OUTD) {
        float acc = b[o];
        const float* wrow = W + (size_t)o * HID;
#pragma unroll 4
        for (int k = 0; k < HID; k++) acc += hsm[k] * wrow[k];
        out[(size_t)bidx * OUTD + o] = acc;
    }
}

extern "C" void kernel_launch(void* const* d_in, const int* in_sizes, int n_in,
                              void* d_out, int out_size, void* d_ws, size_t ws_size,
                              hipStream_t stream) {
    const float* x    = (const float*)d_in[0];
    const float* Wih0 = (const float*)d_in[1];
    const float* Whh0 = (const float*)d_in[2];
    const float* bih0 = (const float*)d_in[3];
    const float* bhh0 = (const float*)d_in[4];
    const float* Wih1 = (const float*)d_in[5];
    const float* Whh1 = (const float*)d_in[6];
    const float* bih1 = (const float*)d_in[7];
    const float* bhh1 = (const float*)d_in[8];
    const float* fcW  = (const float*)d_in[9];
    const float* fcb  = (const float*)d_in[10];
    float* out = (float*)d_out;

    char* ws = (char*)d_ws;
    size_t off = 0;
    auto walloc = [&](size_t bytes) {
        void* p = ws + off;
        off = (off + bytes + 255) & ~(size_t)255;
        return p;
    };

    const int M = BATCH * SEQT;                       // 51200
    unsigned short* xb   = (unsigned short*)walloc((size_t)XSZ * 2);         // 13.1 MB
    float*          gx0  = (float*)         walloc((size_t)2 * SLOTP_F * 4); // 39.3 MB
    float*          gx1  = (float*)         walloc((size_t)2 * SLOTP_F * 4); // 39.3 MB
    unsigned short* h1b  = (unsigned short*)walloc((size_t)M * HID * 2);     // 26.2 MB
    unsigned short* w0b  = (unsigned short*)walloc((size_t)W0SZ * 2);
    unsigned short* wh0b = (unsigned short*)walloc((size_t)WHSZ * 2);
    unsigned short* w1b  = (unsigned short*)walloc((size_t)WHSZ * 2);
    unsigned short* wh1b = (unsigned short*)walloc((size_t)WHSZ * 2);
    float*          bc0  = (float*)         walloc(G3 * 4);
    float*          bc1  = (float*)         walloc(G3 * 4);
    float*          hst0 = (float*)         walloc((size_t)BATCH * HID * 4);
    float*          hst1 = (float*)         walloc((size_t)BATCH * HID * 4);

    cvt_all     <<<2048, 256, 0, stream>>>(x, Wih0, Whh0, Wih1, Whh1,
                                           xb, w0b, wh0b, w1b, wh1b);
    combine_bias<<<6,    256, 0, stream>>>(bih0, bhh0, bih1, bhh1, bc0, bc1);

    // pipeline: launch c = { gemm0(c) | scan0(c-1) | gemm1(c-2) | scan1(c-3) }
    for (int c = 0; c <= NC + 2; ++c)
        pipe<<<256, 512, 0, stream>>>(c, xb, h1b, w0b, w1b, bc0, bc1,
                                      gx0, gx1, wh0b, wh1b, bhh0, bhh1, hst0, hst1);

    fc_kernel<<<BATCH, 128, 0, stream>>>(hst1, fcW, fcb, out);
}